// Round 6
// baseline (5238.477 us; speedup 1.0000x reference)
//
#include <hip/hip_runtime.h>
#include <hip/hip_bf16.h>
#include <stdint.h>

// Problem constants (GlobalAttentionNet): N=100000 nodes, F=H=128, E=1.6M edges,
// G=512 graphs, C=2 classes, 3 SAGEConv layers (mean agg) + attn pooling + MLP.
static constexpr int HD = 128;   // hidden/feature dim (F == H == 128)

// ---------------------------------------------------------------------------
// int64-vs-int32 detection for index inputs (JAX x64-off => int32; else int64).
// int64 values < 2^31 have zero high words; 256 consecutive zero odd-words is
// impossible for random int32 edge ids in [0, 100000).
__global__ void detect_i64_kernel(const unsigned* __restrict__ raw, int* __restrict__ flag) {
    if (blockIdx.x == 0 && threadIdx.x == 0) {
        int is64 = 1;
        for (int i = 0; i < 256; ++i) {
            if (raw[2 * i + 1] != 0u) { is64 = 0; break; }
        }
        *flag = is64;
    }
}

__global__ void convert_idx_kernel(const void* __restrict__ p, int* __restrict__ out,
                                   int n, const int* __restrict__ flag) {
    const bool is64 = (*flag != 0);
    int stride = gridDim.x * blockDim.x;
    for (int i = blockIdx.x * blockDim.x + threadIdx.x; i < n; i += stride) {
        out[i] = is64 ? (int)(((const long long*)p)[i]) : ((const int*)p)[i];
    }
}

// ---------------------------------------------------------------------------
__global__ void deg_kernel(const int* __restrict__ dst, float* __restrict__ deg, int E) {
    int stride = gridDim.x * blockDim.x;
    for (int i = blockIdx.x * blockDim.x + threadIdx.x; i < E; i += stride)
        unsafeAtomicAdd(&deg[dst[i]], 1.0f);
}

__global__ void invdeg_kernel(float* __restrict__ deg, int N) {
    int i = blockIdx.x * blockDim.x + threadIdx.x;
    if (i < N) deg[i] = 1.0f / fmaxf(deg[i], 1.0f);
}

// scatter-add: one wave per edge; lane handles 2 consecutive floats.
__global__ void scatter_kernel(const float* __restrict__ feats, const int* __restrict__ src,
                               const int* __restrict__ dst, float* __restrict__ agg, int E) {
    int wid  = (blockIdx.x * blockDim.x + threadIdx.x) >> 6;
    int lane = threadIdx.x & 63;
    int nw   = (gridDim.x * blockDim.x) >> 6;
    for (int e = wid; e < E; e += nw) {
        int s = src[e], d = dst[e];
        float2 v = ((const float2*)(feats + (size_t)s * HD))[lane];
        float* o = agg + (size_t)d * HD + lane * 2;
        unsafeAtomicAdd(o,     v.x);
        unsafeAtomicAdd(o + 1, v.y);
    }
}

// fused SAGE layer: out = relu(mean @ w_l + b + x @ w_r), written in-place over agg.
// 8 rows x 128 cols per 256-thread block; rows staged in LDS.
__global__ __launch_bounds__(256) void sage_layer_kernel(
    const float* __restrict__ in, float* __restrict__ agg,
    const float* __restrict__ inv_deg,
    const float* __restrict__ w_l, const float* __restrict__ bias,
    const float* __restrict__ w_r, int N)
{
    __shared__ float sM[8][HD];
    __shared__ float sX[8][HD];
    int r  = threadIdx.x >> 5;
    int c4 = (threadIdx.x & 31) << 2;
    int row = blockIdx.x * 8 + r;
    if (row < N) {
        float4 a  = *(const float4*)(agg + (size_t)row * HD + c4);
        float  id = inv_deg[row];
        sM[r][c4 + 0] = a.x * id; sM[r][c4 + 1] = a.y * id;
        sM[r][c4 + 2] = a.z * id; sM[r][c4 + 3] = a.w * id;
        float4 xv = *(const float4*)(in + (size_t)row * HD + c4);
        sX[r][c4 + 0] = xv.x; sX[r][c4 + 1] = xv.y;
        sX[r][c4 + 2] = xv.z; sX[r][c4 + 3] = xv.w;
    } else {
        sM[r][c4] = sM[r][c4+1] = sM[r][c4+2] = sM[r][c4+3] = 0.f;
        sX[r][c4] = sX[r][c4+1] = sX[r][c4+2] = sX[r][c4+3] = 0.f;
    }
    __syncthreads();

    int j = threadIdx.x & 31;
    float acc0 = bias[j], acc1 = bias[j + 32], acc2 = bias[j + 64], acc3 = bias[j + 96];
    for (int k = 0; k < HD; ++k) {
        float mk = sM[r][k], xk = sX[r][k];
        const float* wl = w_l + k * HD;
        const float* wr = w_r + k * HD;
        acc0 += mk * wl[j]      + xk * wr[j];
        acc1 += mk * wl[j + 32] + xk * wr[j + 32];
        acc2 += mk * wl[j + 64] + xk * wr[j + 64];
        acc3 += mk * wl[j + 96] + xk * wr[j + 96];
    }
    if (row < N) {
        float* o = agg + (size_t)row * HD;
        o[j]      = fmaxf(acc0, 0.f);
        o[j + 32] = fmaxf(acc1, 0.f);
        o[j + 64] = fmaxf(acc2, 0.f);
        o[j + 96] = fmaxf(acc3, 0.f);
    }
}

// gate[i] = dot(h[i], gate_w) + gate_b  (wave per row)
__global__ void gate_kernel(const float* __restrict__ h, const float* __restrict__ gw,
                            const float* __restrict__ gb, float* __restrict__ gate, int N) {
    int wid  = (blockIdx.x * blockDim.x + threadIdx.x) >> 6;
    int lane = threadIdx.x & 63;
    int nw   = (gridDim.x * blockDim.x) >> 6;
    float2 w = ((const float2*)gw)[lane];
    for (int row = wid; row < N; row += nw) {
        float2 v = ((const float2*)(h + (size_t)row * HD))[lane];
        float s = v.x * w.x + v.y * w.y;
        for (int off = 32; off; off >>= 1) s += __shfl_xor(s, off);
        if (lane == 0) gate[row] = s + gb[0];
    }
}

__device__ __forceinline__ int lower_bound_i(const int* a, int n, int key) {
    int lo = 0, hi = n;
    while (lo < hi) { int mid = (lo + hi) >> 1; if (a[mid] < key) lo = mid + 1; else hi = mid; }
    return lo;
}

// per-graph softmax-weighted pooling; block per graph, batch sorted.
__global__ __launch_bounds__(128) void pool_kernel(
    const float* __restrict__ h, const float* __restrict__ gate,
    const int* __restrict__ batch, float* __restrict__ pooled, int N)
{
    int g = blockIdx.x;
    int t = threadIdx.x;
    int start = lower_bound_i(batch, N, g);
    int end   = lower_bound_i(batch, N, g + 1);
    __shared__ float sred[128];

    float m = -3.4e38f;
    for (int i = start + t; i < end; i += 128) m = fmaxf(m, gate[i]);
    sred[t] = m; __syncthreads();
    for (int s = 64; s; s >>= 1) { if (t < s) sred[t] = fmaxf(sred[t], sred[t + s]); __syncthreads(); }
    float gmax = sred[0]; __syncthreads();

    float ss = 0.f;
    for (int i = start + t; i < end; i += 128) ss += __expf(gate[i] - gmax);
    sred[t] = ss; __syncthreads();
    for (int s = 64; s; s >>= 1) { if (t < s) sred[t] += sred[t + s]; __syncthreads(); }
    float denom = sred[0]; __syncthreads();

    float acc = 0.f;
    for (int base = start; base < end; base += 128) {
        int cnt = min(128, end - base);
        if (t < cnt) sred[t] = __expf(gate[base + t] - gmax);
        __syncthreads();
        for (int i = 0; i < cnt; ++i)
            acc += h[(size_t)(base + i) * HD + t] * sred[i];
        __syncthreads();
    }
    pooled[(size_t)g * HD + t] = (end > start) ? acc / denom : 0.f;
}

// MLP head: out = sigmoid(relu(pooled @ lin1 + b1) @ lin2 + b2); block per graph.
__global__ __launch_bounds__(128) void head_kernel(
    const float* __restrict__ pooled,
    const float* __restrict__ w1, const float* __restrict__ b1,
    const float* __restrict__ w2, const float* __restrict__ b2,
    float* __restrict__ out)
{
    int g = blockIdx.x, t = threadIdx.x;
    __shared__ float sp[128];
    __shared__ float sh[128];
    sp[t] = pooled[(size_t)g * HD + t];
    __syncthreads();
    float acc = b1[t];
    for (int k = 0; k < HD; ++k) acc += sp[k] * w1[k * HD + t];
    sh[t] = fmaxf(acc, 0.f);
    __syncthreads();
    if (t < 2) {
        float a = b2[t];
        for (int k = 0; k < HD; ++k) a += sh[k] * w2[k * 2 + t];
        out[g * 2 + t] = 1.f / (1.f + __expf(-a));
    }
}

// ---------------------------------------------------------------------------
extern "C" void kernel_launch(void* const* d_in, const int* in_sizes, int n_in,
                              void* d_out, int out_size, void* d_ws, size_t ws_size,
                              hipStream_t stream) {
    const float* x      = (const float*)d_in[0];
    const void*  eidx   = d_in[1];
    const void*  batchp = d_in[2];
    const float* w1_l   = (const float*)d_in[3];
    const float* b1     = (const float*)d_in[4];
    const float* w1_r   = (const float*)d_in[5];
    const float* ws_l   = (const float*)d_in[6];
    const float* bs     = (const float*)d_in[7];
    const float* ws_r   = (const float*)d_in[8];
    const float* gate_w = (const float*)d_in[9];
    const float* gate_b = (const float*)d_in[10];
    const float* lin1_w = (const float*)d_in[11];
    const float* lin1_b = (const float*)d_in[12];
    const float* lin2_w = (const float*)d_in[13];
    const float* lin2_b = (const float*)d_in[14];

    const int N = in_sizes[2];        // 100000
    const int E = in_sizes[1] / 2;    // 1600000
    const int G = out_size / 2;       // 512

    // workspace layout (all 16B aligned)
    char* w = (char*)d_ws;
    int*   flag    = (int*)w;
    int*   idx32   = (int*)(w + 256);
    int*   batch32 = idx32 + 2 * (size_t)E;
    float* deg     = (float*)(batch32 + N);
    float* gate    = deg + N;
    float* pooled  = gate + N;
    float* B1      = pooled + (size_t)G * HD;
    float* B2      = B1 + (size_t)N * HD;

    const int* src = idx32;
    const int* dst = idx32 + E;

    // index conversion
    detect_i64_kernel<<<1, 64, 0, stream>>>((const unsigned*)eidx, flag);
    convert_idx_kernel<<<2048, 256, 0, stream>>>(eidx, idx32, 2 * E, flag);
    convert_idx_kernel<<<512, 256, 0, stream>>>(batchp, batch32, N, flag);

    // degree (shared across layers), then invert in place
    hipMemsetAsync(deg, 0, (size_t)N * 4, stream);
    deg_kernel<<<2048, 256, 0, stream>>>(dst, deg, E);
    invdeg_kernel<<<(N + 255) / 256, 256, 0, stream>>>(deg, N);

    const size_t featB = (size_t)N * HD * 4;
    const int gemm_grid = (N + 7) / 8;

    // layer 1: in = x, agg = B1 (in-place output)
    hipMemsetAsync(B1, 0, featB, stream);
    scatter_kernel<<<8192, 256, 0, stream>>>(x, src, dst, B1, E);
    sage_layer_kernel<<<gemm_grid, 256, 0, stream>>>(x, B1, deg, w1_l, b1, w1_r, N);

    // layer 2: in = B1, agg = B2
    hipMemsetAsync(B2, 0, featB, stream);
    scatter_kernel<<<8192, 256, 0, stream>>>(B1, src, dst, B2, E);
    sage_layer_kernel<<<gemm_grid, 256, 0, stream>>>(B1, B2, deg, ws_l, bs, ws_r, N);

    // layer 3: in = B2, agg = B1
    hipMemsetAsync(B1, 0, featB, stream);
    scatter_kernel<<<8192, 256, 0, stream>>>(B2, src, dst, B1, E);
    sage_layer_kernel<<<gemm_grid, 256, 0, stream>>>(B2, B1, deg,
                                                     ws_l + HD * HD, bs + HD, ws_r + HD * HD, N);

    // gate -> pool -> head
    gate_kernel<<<1024, 256, 0, stream>>>(B1, gate_w, gate_b, gate, N);
    pool_kernel<<<G, 128, 0, stream>>>(B1, gate, batch32, pooled, N);
    head_kernel<<<G, 128, 0, stream>>>(pooled, lin1_w, lin1_b, lin2_w, lin2_b, (float*)d_out);
}

// Round 8
// 2100.800 us; speedup vs baseline: 2.4936x; 2.4936x over previous
//
#include <hip/hip_runtime.h>
#include <hip/hip_bf16.h>
#include <stdint.h>

// GlobalAttentionNet: N=100000 nodes, F=H=128, E=1.6M edges, G=512 graphs, C=2.
// R6: scatter-atomics (3x1280us, WRITE 1.6GB each) -> CSR gather (write-once).
static constexpr int HD = 128;

// ---------------------------------------------------------------------------
// int64-vs-int32 detection for index inputs.
__global__ void detect_i64_kernel(const unsigned* __restrict__ raw, int* __restrict__ flag) {
    if (blockIdx.x == 0 && threadIdx.x == 0) {
        int is64 = 1;
        for (int i = 0; i < 256; ++i) {
            if (raw[2 * i + 1] != 0u) { is64 = 0; break; }
        }
        *flag = is64;
    }
}

__global__ void convert_idx_kernel(const void* __restrict__ p, int* __restrict__ out,
                                   int n, const int* __restrict__ flag) {
    const bool is64 = (*flag != 0);
    int stride = gridDim.x * blockDim.x;
    for (int i = blockIdx.x * blockDim.x + threadIdx.x; i < n; i += stride) {
        out[i] = is64 ? (int)(((const long long*)p)[i]) : ((const int*)p)[i];
    }
}

// ---------------------------------------------------------------------------
// CSR build: histogram -> single-block scan -> cursor fill.
__global__ void count_kernel(const int* __restrict__ dst, int* __restrict__ cnt, int E) {
    int stride = gridDim.x * blockDim.x;
    for (int i = blockIdx.x * blockDim.x + threadIdx.x; i < E; i += stride)
        atomicAdd(&cnt[dst[i]], 1);
}

// single-block Hillis-Steele scan over N elements (1024-wide chunks, serial carry).
__global__ __launch_bounds__(1024) void scan_kernel(const int* __restrict__ cnt,
                                                    int* __restrict__ row_ptr,
                                                    float* __restrict__ inv_deg, int N) {
    __shared__ int s[1024];
    __shared__ int carry;
    int t = threadIdx.x;
    if (t == 0) carry = 0;
    __syncthreads();
    for (int base = 0; base < N; base += 1024) {
        int i = base + t;
        int v = (i < N) ? cnt[i] : 0;
        s[t] = v; __syncthreads();
        for (int off = 1; off < 1024; off <<= 1) {
            int add = (t >= off) ? s[t - off] : 0;
            __syncthreads();
            s[t] += add;
            __syncthreads();
        }
        if (i < N) {
            row_ptr[i] = carry + s[t] - v;          // exclusive
            inv_deg[i] = 1.0f / fmaxf((float)v, 1.0f);
        }
        __syncthreads();                            // all carry reads done
        if (t == 1023) carry += s[1023];
        __syncthreads();
    }
    if (t == 0) row_ptr[N] = carry;
}

__global__ void copy_int_kernel(const int* __restrict__ in, int* __restrict__ out, int n) {
    int stride = gridDim.x * blockDim.x;
    for (int i = blockIdx.x * blockDim.x + threadIdx.x; i < n; i += stride)
        out[i] = in[i];
}

__global__ void fill_kernel(const int* __restrict__ src, const int* __restrict__ dst,
                            int* __restrict__ cursor, int* __restrict__ sorted_src, int E) {
    int stride = gridDim.x * blockDim.x;
    for (int e = blockIdx.x * blockDim.x + threadIdx.x; e < E; e += stride) {
        int pos = atomicAdd(&cursor[dst[e]], 1);
        sorted_src[pos] = src[e];
    }
}

// ---------------------------------------------------------------------------
// gather mean: one wave per dst node; lane holds 2 consecutive floats.
// Writes mean (pre-scaled by inv_deg) exactly once -- no atomics, no memset.
__global__ __launch_bounds__(256) void gather_kernel(
    const float* __restrict__ feats, const int* __restrict__ row_ptr,
    const int* __restrict__ sorted_src, const float* __restrict__ inv_deg,
    float* __restrict__ mean_out, int N)
{
    int w    = (blockIdx.x * blockDim.x + threadIdx.x) >> 6;
    int lane = threadIdx.x & 63;
    if (w >= N) return;
    int beg = row_ptr[w], end = row_ptr[w + 1];
    float ax = 0.f, ay = 0.f;
    for (int e = beg; e < end; ++e) {
        int s = sorted_src[e];
        float2 v = ((const float2*)(feats + (size_t)s * HD))[lane];
        ax += v.x; ay += v.y;
    }
    float id = inv_deg[w];
    float2 o; o.x = ax * id; o.y = ay * id;
    ((float2*)(mean_out + (size_t)w * HD))[lane] = o;
}

// fused SAGE layer: out = relu(mean @ w_l + b + x @ w_r), in-place over mean buf.
__global__ __launch_bounds__(256) void sage_layer_kernel(
    const float* __restrict__ in, float* __restrict__ h,
    const float* __restrict__ w_l, const float* __restrict__ bias,
    const float* __restrict__ w_r, int N)
{
    __shared__ float sM[8][HD];
    __shared__ float sX[8][HD];
    int r  = threadIdx.x >> 5;
    int c4 = (threadIdx.x & 31) << 2;
    int row = blockIdx.x * 8 + r;
    if (row < N) {
        float4 a  = *(const float4*)(h + (size_t)row * HD + c4);
        sM[r][c4 + 0] = a.x; sM[r][c4 + 1] = a.y;
        sM[r][c4 + 2] = a.z; sM[r][c4 + 3] = a.w;
        float4 xv = *(const float4*)(in + (size_t)row * HD + c4);
        sX[r][c4 + 0] = xv.x; sX[r][c4 + 1] = xv.y;
        sX[r][c4 + 2] = xv.z; sX[r][c4 + 3] = xv.w;
    } else {
        sM[r][c4] = sM[r][c4+1] = sM[r][c4+2] = sM[r][c4+3] = 0.f;
        sX[r][c4] = sX[r][c4+1] = sX[r][c4+2] = sX[r][c4+3] = 0.f;
    }
    __syncthreads();

    int j = threadIdx.x & 31;
    float acc0 = bias[j], acc1 = bias[j + 32], acc2 = bias[j + 64], acc3 = bias[j + 96];
    for (int k = 0; k < HD; ++k) {
        float mk = sM[r][k], xk = sX[r][k];
        const float* wl = w_l + k * HD;
        const float* wr = w_r + k * HD;
        acc0 += mk * wl[j]      + xk * wr[j];
        acc1 += mk * wl[j + 32] + xk * wr[j + 32];
        acc2 += mk * wl[j + 64] + xk * wr[j + 64];
        acc3 += mk * wl[j + 96] + xk * wr[j + 96];
    }
    if (row < N) {
        float* o = h + (size_t)row * HD;
        o[j]      = fmaxf(acc0, 0.f);
        o[j + 32] = fmaxf(acc1, 0.f);
        o[j + 64] = fmaxf(acc2, 0.f);
        o[j + 96] = fmaxf(acc3, 0.f);
    }
}

// gate[i] = dot(h[i], gate_w) + gate_b  (wave per row)
__global__ void gate_kernel(const float* __restrict__ h, const float* __restrict__ gw,
                            const float* __restrict__ gb, float* __restrict__ gate, int N) {
    int wid  = (blockIdx.x * blockDim.x + threadIdx.x) >> 6;
    int lane = threadIdx.x & 63;
    int nw   = (gridDim.x * blockDim.x) >> 6;
    float2 w = ((const float2*)gw)[lane];
    for (int row = wid; row < N; row += nw) {
        float2 v = ((const float2*)(h + (size_t)row * HD))[lane];
        float s = v.x * w.x + v.y * w.y;
        for (int off = 32; off; off >>= 1) s += __shfl_xor(s, off);
        if (lane == 0) gate[row] = s + gb[0];
    }
}

__device__ __forceinline__ int lower_bound_i(const int* a, int n, int key) {
    int lo = 0, hi = n;
    while (lo < hi) { int mid = (lo + hi) >> 1; if (a[mid] < key) lo = mid + 1; else hi = mid; }
    return lo;
}

// per-graph softmax-weighted pooling; block per graph, batch sorted.
__global__ __launch_bounds__(128) void pool_kernel(
    const float* __restrict__ h, const float* __restrict__ gate,
    const int* __restrict__ batch, float* __restrict__ pooled, int N)
{
    int g = blockIdx.x;
    int t = threadIdx.x;
    int start = lower_bound_i(batch, N, g);
    int end   = lower_bound_i(batch, N, g + 1);
    __shared__ float sred[128];

    float m = -3.4e38f;
    for (int i = start + t; i < end; i += 128) m = fmaxf(m, gate[i]);
    sred[t] = m; __syncthreads();
    for (int s = 64; s; s >>= 1) { if (t < s) sred[t] = fmaxf(sred[t], sred[t + s]); __syncthreads(); }
    float gmax = sred[0]; __syncthreads();

    float ss = 0.f;
    for (int i = start + t; i < end; i += 128) ss += __expf(gate[i] - gmax);
    sred[t] = ss; __syncthreads();
    for (int s = 64; s; s >>= 1) { if (t < s) sred[t] += sred[t + s]; __syncthreads(); }
    float denom = sred[0]; __syncthreads();

    float acc = 0.f;
    for (int base = start; base < end; base += 128) {
        int cnt = min(128, end - base);
        if (t < cnt) sred[t] = __expf(gate[base + t] - gmax);
        __syncthreads();
        for (int i = 0; i < cnt; ++i)
            acc += h[(size_t)(base + i) * HD + t] * sred[i];
        __syncthreads();
    }
    pooled[(size_t)g * HD + t] = (end > start) ? acc / denom : 0.f;
}

// MLP head: out = sigmoid(relu(pooled @ lin1 + b1) @ lin2 + b2); block per graph.
__global__ __launch_bounds__(128) void head_kernel(
    const float* __restrict__ pooled,
    const float* __restrict__ w1, const float* __restrict__ b1,
    const float* __restrict__ w2, const float* __restrict__ b2,
    float* __restrict__ out)
{
    int g = blockIdx.x, t = threadIdx.x;
    __shared__ float sp[128];
    __shared__ float sh[128];
    sp[t] = pooled[(size_t)g * HD + t];
    __syncthreads();
    float acc = b1[t];
    for (int k = 0; k < HD; ++k) acc += sp[k] * w1[k * HD + t];
    sh[t] = fmaxf(acc, 0.f);
    __syncthreads();
    if (t < 2) {
        float a = b2[t];
        for (int k = 0; k < HD; ++k) a += sh[k] * w2[k * 2 + t];
        out[g * 2 + t] = 1.f / (1.f + __expf(-a));
    }
}

// ---------------------------------------------------------------------------
extern "C" void kernel_launch(void* const* d_in, const int* in_sizes, int n_in,
                              void* d_out, int out_size, void* d_ws, size_t ws_size,
                              hipStream_t stream) {
    const float* x      = (const float*)d_in[0];
    const void*  eidx   = d_in[1];
    const void*  batchp = d_in[2];
    const float* w1_l   = (const float*)d_in[3];
    const float* b1     = (const float*)d_in[4];
    const float* w1_r   = (const float*)d_in[5];
    const float* ws_l   = (const float*)d_in[6];
    const float* bs     = (const float*)d_in[7];
    const float* ws_r   = (const float*)d_in[8];
    const float* gate_w = (const float*)d_in[9];
    const float* gate_b = (const float*)d_in[10];
    const float* lin1_w = (const float*)d_in[11];
    const float* lin1_b = (const float*)d_in[12];
    const float* lin2_w = (const float*)d_in[13];
    const float* lin2_b = (const float*)d_in[14];

    const int N = in_sizes[2];        // 100000
    const int E = in_sizes[1] / 2;    // 1600000
    const int G = out_size / 2;       // 512

    // workspace layout (all offsets multiples of 16B; row_ptr last since N+1 is odd)
    char* w = (char*)d_ws;
    int*   flag       = (int*)w;                      // 256 B block
    int*   idx32      = (int*)(w + 256);              // 2E
    int*   sorted_src = idx32 + 2 * (size_t)E;        // E
    int*   batch32    = sorted_src + E;               // N
    int*   cnt        = batch32 + N;                  // N
    int*   cursor     = cnt + N;                      // N
    float* inv_deg    = (float*)(cursor + N);         // N
    float* gate       = inv_deg + N;                  // N
    float* pooled     = gate + N;                     // G*HD
    float* B1         = pooled + (size_t)G * HD;      // N*HD
    float* B2         = B1 + (size_t)N * HD;          // N*HD
    int*   row_ptr    = (int*)(B2 + (size_t)N * HD);  // N+1

    const int* src = idx32;
    const int* dst = idx32 + E;

    // index conversion
    detect_i64_kernel<<<1, 64, 0, stream>>>((const unsigned*)eidx, flag);
    convert_idx_kernel<<<2048, 256, 0, stream>>>(eidx, idx32, 2 * E, flag);
    convert_idx_kernel<<<512, 256, 0, stream>>>(batchp, batch32, N, flag);

    // CSR build (once; shared by all 3 layers)
    hipMemsetAsync(cnt, 0, (size_t)N * 4, stream);
    count_kernel<<<2048, 256, 0, stream>>>(dst, cnt, E);
    scan_kernel<<<1, 1024, 0, stream>>>(cnt, row_ptr, inv_deg, N);
    copy_int_kernel<<<512, 256, 0, stream>>>(row_ptr, cursor, N);
    fill_kernel<<<2048, 256, 0, stream>>>(src, dst, cursor, sorted_src, E);

    const int gather_grid = (N * 64 + 255) / 256;   // one wave per node
    const int gemm_grid   = (N + 7) / 8;

    // layer 1: in = x -> mean in B1 -> h1 in-place in B1
    gather_kernel<<<gather_grid, 256, 0, stream>>>(x, row_ptr, sorted_src, inv_deg, B1, N);
    sage_layer_kernel<<<gemm_grid, 256, 0, stream>>>(x, B1, w1_l, b1, w1_r, N);

    // layer 2: in = B1 -> mean in B2 -> h2 in-place in B2
    gather_kernel<<<gather_grid, 256, 0, stream>>>(B1, row_ptr, sorted_src, inv_deg, B2, N);
    sage_layer_kernel<<<gemm_grid, 256, 0, stream>>>(B1, B2, ws_l, bs, ws_r, N);

    // layer 3: in = B2 -> mean in B1 -> h3 in-place in B1
    gather_kernel<<<gather_grid, 256, 0, stream>>>(B2, row_ptr, sorted_src, inv_deg, B1, N);
    sage_layer_kernel<<<gemm_grid, 256, 0, stream>>>(B2, B1,
                                                     ws_l + HD * HD, bs + HD, ws_r + HD * HD, N);

    // gate -> pool -> head
    gate_kernel<<<1024, 256, 0, stream>>>(B1, gate_w, gate_b, gate, N);
    pool_kernel<<<G, 128, 0, stream>>>(B1, gate, batch32, pooled, N);
    head_kernel<<<G, 128, 0, stream>>>(pooled, lin1_w, lin1_b, lin2_w, lin2_b, (float*)d_out);
}

// Round 9
// 1322.248 us; speedup vs baseline: 3.9618x; 1.5888x over previous
//
#include <hip/hip_runtime.h>
#include <hip/hip_bf16.h>
#include <stdint.h>

// GlobalAttentionNet: N=100000 nodes, F=H=128, E=1.6M edges, G=512 graphs, C=2.
// R6: scatter-atomics -> CSR gather (5238 -> 2101 us).
// R8: sage layer GEMM was latency-bound on per-iter global weight loads
//     (VALUBusy 21.7%); rewrite as LDS-tiled 64x128 GEMM, 8x4 acc/thread.
static constexpr int HD = 128;

// ---------------------------------------------------------------------------
// int64-vs-int32 detection for index inputs.
__global__ void detect_i64_kernel(const unsigned* __restrict__ raw, int* __restrict__ flag) {
    if (blockIdx.x == 0 && threadIdx.x == 0) {
        int is64 = 1;
        for (int i = 0; i < 256; ++i) {
            if (raw[2 * i + 1] != 0u) { is64 = 0; break; }
        }
        *flag = is64;
    }
}

__global__ void convert_idx_kernel(const void* __restrict__ p, int* __restrict__ out,
                                   int n, const int* __restrict__ flag) {
    const bool is64 = (*flag != 0);
    int stride = gridDim.x * blockDim.x;
    for (int i = blockIdx.x * blockDim.x + threadIdx.x; i < n; i += stride) {
        out[i] = is64 ? (int)(((const long long*)p)[i]) : ((const int*)p)[i];
    }
}

// ---------------------------------------------------------------------------
// CSR build: histogram -> single-block scan -> cursor fill.
__global__ void count_kernel(const int* __restrict__ dst, int* __restrict__ cnt, int E) {
    int stride = gridDim.x * blockDim.x;
    for (int i = blockIdx.x * blockDim.x + threadIdx.x; i < E; i += stride)
        atomicAdd(&cnt[dst[i]], 1);
}

// single-block Hillis-Steele scan over N elements (1024-wide chunks, serial carry).
__global__ __launch_bounds__(1024) void scan_kernel(const int* __restrict__ cnt,
                                                    int* __restrict__ row_ptr,
                                                    float* __restrict__ inv_deg, int N) {
    __shared__ int s[1024];
    __shared__ int carry;
    int t = threadIdx.x;
    if (t == 0) carry = 0;
    __syncthreads();
    for (int base = 0; base < N; base += 1024) {
        int i = base + t;
        int v = (i < N) ? cnt[i] : 0;
        s[t] = v; __syncthreads();
        for (int off = 1; off < 1024; off <<= 1) {
            int add = (t >= off) ? s[t - off] : 0;
            __syncthreads();
            s[t] += add;
            __syncthreads();
        }
        if (i < N) {
            row_ptr[i] = carry + s[t] - v;          // exclusive
            inv_deg[i] = 1.0f / fmaxf((float)v, 1.0f);
        }
        __syncthreads();                            // all carry reads done
        if (t == 1023) carry += s[1023];
        __syncthreads();
    }
    if (t == 0) row_ptr[N] = carry;
}

__global__ void copy_int_kernel(const int* __restrict__ in, int* __restrict__ out, int n) {
    int stride = gridDim.x * blockDim.x;
    for (int i = blockIdx.x * blockDim.x + threadIdx.x; i < n; i += stride)
        out[i] = in[i];
}

__global__ void fill_kernel(const int* __restrict__ src, const int* __restrict__ dst,
                            int* __restrict__ cursor, int* __restrict__ sorted_src, int E) {
    int stride = gridDim.x * blockDim.x;
    for (int e = blockIdx.x * blockDim.x + threadIdx.x; e < E; e += stride) {
        int pos = atomicAdd(&cursor[dst[e]], 1);
        sorted_src[pos] = src[e];
    }
}

// ---------------------------------------------------------------------------
// gather mean: one wave per dst node; lane holds 2 consecutive floats.
__global__ __launch_bounds__(256) void gather_kernel(
    const float* __restrict__ feats, const int* __restrict__ row_ptr,
    const int* __restrict__ sorted_src, const float* __restrict__ inv_deg,
    float* __restrict__ mean_out, int N)
{
    int w    = (blockIdx.x * blockDim.x + threadIdx.x) >> 6;
    int lane = threadIdx.x & 63;
    if (w >= N) return;
    int beg = row_ptr[w], end = row_ptr[w + 1];
    float ax = 0.f, ay = 0.f;
    for (int e = beg; e < end; ++e) {
        int s = sorted_src[e];
        float2 v = ((const float2*)(feats + (size_t)s * HD))[lane];
        ax += v.x; ay += v.y;
    }
    float id = inv_deg[w];
    float2 o; o.x = ax * id; o.y = ay * id;
    ((float2*)(mean_out + (size_t)w * HD))[lane] = o;
}

// ---------------------------------------------------------------------------
// fused SAGE layer: h = relu(mean @ w_l + b + x @ w_r), in-place over mean buf.
// LDS-tiled: 64 rows x 128 cols per 256-thread block; 8x4 outputs per thread;
// k-chunks of 32, A staged transposed (conflict-free inner reads), B natural.
__global__ __launch_bounds__(256) void sage_layer_kernel(
    const float* __restrict__ in, float* __restrict__ h,
    const float* __restrict__ w_l, const float* __restrict__ bias,
    const float* __restrict__ w_r, int N)
{
    __shared__ float At[32][64];    // [k][row]
    __shared__ float Bt[32][128];   // [k][col]

    const int tid  = threadIdx.x;
    const int rg   = tid >> 5;        // 0..7  (row group: rows rg*8..rg*8+7)
    const int cg   = tid & 31;        // 0..31 (col group: cols cg*4..cg*4+3)
    const int row0 = blockIdx.x * 64;

    // staging coords
    const int row_a = tid >> 2;       // 0..63
    const int kc    = (tid & 3) * 8;  // 0,8,16,24
    const int kb    = tid >> 3;       // 0..31
    const int cb    = (tid & 7) * 16; // 0..112

    float acc[8][4];
    {
        const float4 bv = *(const float4*)(bias + cg * 4);
        #pragma unroll
        for (int i = 0; i < 8; ++i) {
            acc[i][0] = bv.x; acc[i][1] = bv.y; acc[i][2] = bv.z; acc[i][3] = bv.w;
        }
    }

    #pragma unroll
    for (int phase = 0; phase < 2; ++phase) {
        const float* A = phase ? in  : h;     // phase0: mean (in h buf); phase1: x
        const float* W = phase ? w_r : w_l;
        for (int k0 = 0; k0 < HD; k0 += 32) {
            __syncthreads();
            // stage A transposed: At[k][row]
            {
                int grow = row0 + row_a;
                float4 v0 = make_float4(0.f, 0.f, 0.f, 0.f), v1 = v0;
                if (grow < N) {
                    const float* ap = A + (size_t)grow * HD + k0 + kc;
                    v0 = *(const float4*)(ap);
                    v1 = *(const float4*)(ap + 4);
                }
                At[kc + 0][row_a] = v0.x; At[kc + 1][row_a] = v0.y;
                At[kc + 2][row_a] = v0.z; At[kc + 3][row_a] = v0.w;
                At[kc + 4][row_a] = v1.x; At[kc + 5][row_a] = v1.y;
                At[kc + 6][row_a] = v1.z; At[kc + 7][row_a] = v1.w;
            }
            // stage B natural: Bt[k][col] (coalesced float4s)
            {
                const float* wrow = W + (size_t)(k0 + kb) * HD + cb;
                *(float4*)&Bt[kb][cb + 0]  = *(const float4*)(wrow + 0);
                *(float4*)&Bt[kb][cb + 4]  = *(const float4*)(wrow + 4);
                *(float4*)&Bt[kb][cb + 8]  = *(const float4*)(wrow + 8);
                *(float4*)&Bt[kb][cb + 12] = *(const float4*)(wrow + 12);
            }
            __syncthreads();

            #pragma unroll
            for (int kk = 0; kk < 32; ++kk) {
                float4 bv = *(const float4*)&Bt[kk][cg * 4];
                float4 a0 = *(const float4*)&At[kk][rg * 8];
                float4 a1 = *(const float4*)&At[kk][rg * 8 + 4];
                float av[8] = {a0.x, a0.y, a0.z, a0.w, a1.x, a1.y, a1.z, a1.w};
                float bw[4] = {bv.x, bv.y, bv.z, bv.w};
                #pragma unroll
                for (int i = 0; i < 8; ++i)
                    #pragma unroll
                    for (int j = 0; j < 4; ++j)
                        acc[i][j] += av[i] * bw[j];
            }
        }
    }

    // write out (after both phases; in-place over h is safe: block reads only
    // its own rows, all reads precede writes)
    #pragma unroll
    for (int i = 0; i < 8; ++i) {
        int r = row0 + rg * 8 + i;
        if (r < N) {
            float4 o;
            o.x = fmaxf(acc[i][0], 0.f);
            o.y = fmaxf(acc[i][1], 0.f);
            o.z = fmaxf(acc[i][2], 0.f);
            o.w = fmaxf(acc[i][3], 0.f);
            *(float4*)(h + (size_t)r * HD + cg * 4) = o;
        }
    }
}

// gate[i] = dot(h[i], gate_w) + gate_b  (wave per row)
__global__ void gate_kernel(const float* __restrict__ h, const float* __restrict__ gw,
                            const float* __restrict__ gb, float* __restrict__ gate, int N) {
    int wid  = (blockIdx.x * blockDim.x + threadIdx.x) >> 6;
    int lane = threadIdx.x & 63;
    int nw   = (gridDim.x * blockDim.x) >> 6;
    float2 w = ((const float2*)gw)[lane];
    for (int row = wid; row < N; row += nw) {
        float2 v = ((const float2*)(h + (size_t)row * HD))[lane];
        float s = v.x * w.x + v.y * w.y;
        for (int off = 32; off; off >>= 1) s += __shfl_xor(s, off);
        if (lane == 0) gate[row] = s + gb[0];
    }
}

__device__ __forceinline__ int lower_bound_i(const int* a, int n, int key) {
    int lo = 0, hi = n;
    while (lo < hi) { int mid = (lo + hi) >> 1; if (a[mid] < key) lo = mid + 1; else hi = mid; }
    return lo;
}

// per-graph softmax-weighted pooling; block per graph, batch sorted.
__global__ __launch_bounds__(128) void pool_kernel(
    const float* __restrict__ h, const float* __restrict__ gate,
    const int* __restrict__ batch, float* __restrict__ pooled, int N)
{
    int g = blockIdx.x;
    int t = threadIdx.x;
    int start = lower_bound_i(batch, N, g);
    int end   = lower_bound_i(batch, N, g + 1);
    __shared__ float sred[128];

    float m = -3.4e38f;
    for (int i = start + t; i < end; i += 128) m = fmaxf(m, gate[i]);
    sred[t] = m; __syncthreads();
    for (int s = 64; s; s >>= 1) { if (t < s) sred[t] = fmaxf(sred[t], sred[t + s]); __syncthreads(); }
    float gmax = sred[0]; __syncthreads();

    float ss = 0.f;
    for (int i = start + t; i < end; i += 128) ss += __expf(gate[i] - gmax);
    sred[t] = ss; __syncthreads();
    for (int s = 64; s; s >>= 1) { if (t < s) sred[t] += sred[t + s]; __syncthreads(); }
    float denom = sred[0]; __syncthreads();

    float acc = 0.f;
    for (int base = start; base < end; base += 128) {
        int cnt = min(128, end - base);
        if (t < cnt) sred[t] = __expf(gate[base + t] - gmax);
        __syncthreads();
        for (int i = 0; i < cnt; ++i)
            acc += h[(size_t)(base + i) * HD + t] * sred[i];
        __syncthreads();
    }
    pooled[(size_t)g * HD + t] = (end > start) ? acc / denom : 0.f;
}

// MLP head: out = sigmoid(relu(pooled @ lin1 + b1) @ lin2 + b2); block per graph.
__global__ __launch_bounds__(128) void head_kernel(
    const float* __restrict__ pooled,
    const float* __restrict__ w1, const float* __restrict__ b1,
    const float* __restrict__ w2, const float* __restrict__ b2,
    float* __restrict__ out)
{
    int g = blockIdx.x, t = threadIdx.x;
    __shared__ float sp[128];
    __shared__ float sh[128];
    sp[t] = pooled[(size_t)g * HD + t];
    __syncthreads();
    float acc = b1[t];
    for (int k = 0; k < HD; ++k) acc += sp[k] * w1[k * HD + t];
    sh[t] = fmaxf(acc, 0.f);
    __syncthreads();
    if (t < 2) {
        float a = b2[t];
        for (int k = 0; k < HD; ++k) a += sh[k] * w2[k * 2 + t];
        out[g * 2 + t] = 1.f / (1.f + __expf(-a));
    }
}

// ---------------------------------------------------------------------------
extern "C" void kernel_launch(void* const* d_in, const int* in_sizes, int n_in,
                              void* d_out, int out_size, void* d_ws, size_t ws_size,
                              hipStream_t stream) {
    const float* x      = (const float*)d_in[0];
    const void*  eidx   = d_in[1];
    const void*  batchp = d_in[2];
    const float* w1_l   = (const float*)d_in[3];
    const float* b1     = (const float*)d_in[4];
    const float* w1_r   = (const float*)d_in[5];
    const float* ws_l   = (const float*)d_in[6];
    const float* bs     = (const float*)d_in[7];
    const float* ws_r   = (const float*)d_in[8];
    const float* gate_w = (const float*)d_in[9];
    const float* gate_b = (const float*)d_in[10];
    const float* lin1_w = (const float*)d_in[11];
    const float* lin1_b = (const float*)d_in[12];
    const float* lin2_w = (const float*)d_in[13];
    const float* lin2_b = (const float*)d_in[14];

    const int N = in_sizes[2];        // 100000
    const int E = in_sizes[1] / 2;    // 1600000
    const int G = out_size / 2;       // 512

    // workspace layout (all offsets multiples of 16B; row_ptr last since N+1 is odd)
    char* w = (char*)d_ws;
    int*   flag       = (int*)w;                      // 256 B block
    int*   idx32      = (int*)(w + 256);              // 2E
    int*   sorted_src = idx32 + 2 * (size_t)E;        // E
    int*   batch32    = sorted_src + E;               // N
    int*   cnt        = batch32 + N;                  // N
    int*   cursor     = cnt + N;                      // N
    float* inv_deg    = (float*)(cursor + N);         // N
    float* gate       = inv_deg + N;                  // N
    float* pooled     = gate + N;                     // G*HD
    float* B1         = pooled + (size_t)G * HD;      // N*HD
    float* B2         = B1 + (size_t)N * HD;          // N*HD
    int*   row_ptr    = (int*)(B2 + (size_t)N * HD);  // N+1

    const int* src = idx32;
    const int* dst = idx32 + E;

    // index conversion
    detect_i64_kernel<<<1, 64, 0, stream>>>((const unsigned*)eidx, flag);
    convert_idx_kernel<<<2048, 256, 0, stream>>>(eidx, idx32, 2 * E, flag);
    convert_idx_kernel<<<512, 256, 0, stream>>>(batchp, batch32, N, flag);

    // CSR build (once; shared by all 3 layers)
    hipMemsetAsync(cnt, 0, (size_t)N * 4, stream);
    count_kernel<<<2048, 256, 0, stream>>>(dst, cnt, E);
    scan_kernel<<<1, 1024, 0, stream>>>(cnt, row_ptr, inv_deg, N);
    copy_int_kernel<<<512, 256, 0, stream>>>(row_ptr, cursor, N);
    fill_kernel<<<2048, 256, 0, stream>>>(src, dst, cursor, sorted_src, E);

    const int gather_grid = (N * 64 + 255) / 256;   // one wave per node
    const int gemm_grid   = (N + 63) / 64;

    // layer 1: in = x -> mean in B1 -> h1 in-place in B1
    gather_kernel<<<gather_grid, 256, 0, stream>>>(x, row_ptr, sorted_src, inv_deg, B1, N);
    sage_layer_kernel<<<gemm_grid, 256, 0, stream>>>(x, B1, w1_l, b1, w1_r, N);

    // layer 2: in = B1 -> mean in B2 -> h2 in-place in B2
    gather_kernel<<<gather_grid, 256, 0, stream>>>(B1, row_ptr, sorted_src, inv_deg, B2, N);
    sage_layer_kernel<<<gemm_grid, 256, 0, stream>>>(B1, B2, ws_l, bs, ws_r, N);

    // layer 3: in = B2 -> mean in B1 -> h3 in-place in B1
    gather_kernel<<<gather_grid, 256, 0, stream>>>(B2, row_ptr, sorted_src, inv_deg, B1, N);
    sage_layer_kernel<<<gemm_grid, 256, 0, stream>>>(B2, B1,
                                                     ws_l + HD * HD, bs + HD, ws_r + HD * HD, N);

    // gate -> pool -> head
    gate_kernel<<<1024, 256, 0, stream>>>(B1, gate_w, gate_b, gate, N);
    pool_kernel<<<G, 128, 0, stream>>>(B1, gate, batch32, pooled, N);
    head_kernel<<<G, 128, 0, stream>>>(pooled, lin1_w, lin1_b, lin2_w, lin2_b, (float*)d_out);
}

// Round 12
// 1152.809 us; speedup vs baseline: 4.5441x; 1.1470x over previous
//
#include <hip/hip_runtime.h>
#include <hip/hip_bf16.h>
#include <stdint.h>

// GlobalAttentionNet: N=100000 nodes, F=H=128, E=1.6M edges, G=512 graphs, C=2.
// R6: scatter-atomics -> CSR gather (5238 -> 2101 us).
// R8: LDS-tiled 64x128 fp32 GEMM for sage layers (2101 -> 1322 us).
// R9: single-block scan was 189us at 0.18% occupancy -> 3-kernel hierarchical scan.
static constexpr int HD = 128;

// ---------------------------------------------------------------------------
// int64-vs-int32 detection for index inputs.
__global__ void detect_i64_kernel(const unsigned* __restrict__ raw, int* __restrict__ flag) {
    if (blockIdx.x == 0 && threadIdx.x == 0) {
        int is64 = 1;
        for (int i = 0; i < 256; ++i) {
            if (raw[2 * i + 1] != 0u) { is64 = 0; break; }
        }
        *flag = is64;
    }
}

__global__ void convert_idx_kernel(const void* __restrict__ p, int* __restrict__ out,
                                   int n, const int* __restrict__ flag) {
    const bool is64 = (*flag != 0);
    int stride = gridDim.x * blockDim.x;
    for (int i = blockIdx.x * blockDim.x + threadIdx.x; i < n; i += stride) {
        out[i] = is64 ? (int)(((const long long*)p)[i]) : ((const int*)p)[i];
    }
}

// ---------------------------------------------------------------------------
// CSR build: histogram -> hierarchical scan -> cursor fill.
__global__ void count_kernel(const int* __restrict__ dst, int* __restrict__ cnt, int E) {
    int stride = gridDim.x * blockDim.x;
    for (int i = blockIdx.x * blockDim.x + threadIdx.x; i < E; i += stride)
        atomicAdd(&cnt[dst[i]], 1);
}

// scan level 1: per-block exclusive scan (1024 elems/block) + block totals + inv_deg
__global__ __launch_bounds__(1024) void scan1_kernel(const int* __restrict__ cnt,
                                                     int* __restrict__ row_ptr,
                                                     float* __restrict__ inv_deg,
                                                     int* __restrict__ blk_sum, int N) {
    __shared__ int s[1024];
    int t = threadIdx.x;
    int i = blockIdx.x * 1024 + t;
    int v = (i < N) ? cnt[i] : 0;
    s[t] = v;
    __syncthreads();
    for (int off = 1; off < 1024; off <<= 1) {
        int add = (t >= off) ? s[t - off] : 0;
        __syncthreads();
        s[t] += add;
        __syncthreads();
    }
    if (i < N) {
        row_ptr[i] = s[t] - v;                       // block-local exclusive
        inv_deg[i] = 1.0f / fmaxf((float)v, 1.0f);
    }
    if (t == 1023) blk_sum[blockIdx.x] = s[1023];
}

// scan level 2: exclusive scan of block totals (nb <= 128)
__global__ __launch_bounds__(128) void scan2_kernel(int* __restrict__ blk_sum, int nb) {
    __shared__ int s[128];
    int t = threadIdx.x;
    int v = (t < nb) ? blk_sum[t] : 0;
    s[t] = v;
    __syncthreads();
    for (int off = 1; off < 128; off <<= 1) {
        int add = (t >= off) ? s[t - off] : 0;
        __syncthreads();
        s[t] += add;
        __syncthreads();
    }
    if (t < nb) blk_sum[t] = s[t] - v;               // exclusive block offsets
}

// scan level 3: add block offsets; row_ptr[N] = E (sum of degrees == E)
__global__ __launch_bounds__(1024) void scan3_kernel(int* __restrict__ row_ptr,
                                                     const int* __restrict__ blk_sum,
                                                     int N, int E) {
    int i = blockIdx.x * 1024 + threadIdx.x;
    if (i < N) row_ptr[i] += blk_sum[blockIdx.x];
    if (i == 0) row_ptr[N] = E;
}

__global__ void copy_int_kernel(const int* __restrict__ in, int* __restrict__ out, int n) {
    int stride = gridDim.x * blockDim.x;
    for (int i = blockIdx.x * blockDim.x + threadIdx.x; i < n; i += stride)
        out[i] = in[i];
}

__global__ void fill_kernel(const int* __restrict__ src, const int* __restrict__ dst,
                            int* __restrict__ cursor, int* __restrict__ sorted_src, int E) {
    int stride = gridDim.x * blockDim.x;
    for (int e = blockIdx.x * blockDim.x + threadIdx.x; e < E; e += stride) {
        int pos = atomicAdd(&cursor[dst[e]], 1);
        sorted_src[pos] = src[e];
    }
}

// ---------------------------------------------------------------------------
// gather mean: one wave per dst node; lane holds 2 consecutive floats.
__global__ __launch_bounds__(256) void gather_kernel(
    const float* __restrict__ feats, const int* __restrict__ row_ptr,
    const int* __restrict__ sorted_src, const float* __restrict__ inv_deg,
    float* __restrict__ mean_out, int N)
{
    int w    = (blockIdx.x * blockDim.x + threadIdx.x) >> 6;
    int lane = threadIdx.x & 63;
    if (w >= N) return;
    int beg = row_ptr[w], end = row_ptr[w + 1];
    float ax = 0.f, ay = 0.f;
    for (int e = beg; e < end; ++e) {
        int s = sorted_src[e];
        float2 v = ((const float2*)(feats + (size_t)s * HD))[lane];
        ax += v.x; ay += v.y;
    }
    float id = inv_deg[w];
    float2 o; o.x = ax * id; o.y = ay * id;
    ((float2*)(mean_out + (size_t)w * HD))[lane] = o;
}

// ---------------------------------------------------------------------------
// fused SAGE layer: h = relu(mean @ w_l + b + x @ w_r), in-place over mean buf.
// LDS-tiled: 64 rows x 128 cols per 256-thread block; 8x4 outputs per thread.
__global__ __launch_bounds__(256) void sage_layer_kernel(
    const float* __restrict__ in, float* __restrict__ h,
    const float* __restrict__ w_l, const float* __restrict__ bias,
    const float* __restrict__ w_r, int N)
{
    __shared__ float At[32][64];    // [k][row]
    __shared__ float Bt[32][128];   // [k][col]

    const int tid  = threadIdx.x;
    const int rg   = tid >> 5;        // 0..7
    const int cg   = tid & 31;        // 0..31
    const int row0 = blockIdx.x * 64;

    const int row_a = tid >> 2;       // 0..63
    const int kc    = (tid & 3) * 8;  // 0,8,16,24
    const int kb    = tid >> 3;       // 0..31
    const int cb    = (tid & 7) * 16; // 0..112

    float acc[8][4];
    {
        const float4 bv = *(const float4*)(bias + cg * 4);
        #pragma unroll
        for (int i = 0; i < 8; ++i) {
            acc[i][0] = bv.x; acc[i][1] = bv.y; acc[i][2] = bv.z; acc[i][3] = bv.w;
        }
    }

    #pragma unroll
    for (int phase = 0; phase < 2; ++phase) {
        const float* A = phase ? in  : h;
        const float* W = phase ? w_r : w_l;
        for (int k0 = 0; k0 < HD; k0 += 32) {
            __syncthreads();
            {
                int grow = row0 + row_a;
                float4 v0 = make_float4(0.f, 0.f, 0.f, 0.f), v1 = v0;
                if (grow < N) {
                    const float* ap = A + (size_t)grow * HD + k0 + kc;
                    v0 = *(const float4*)(ap);
                    v1 = *(const float4*)(ap + 4);
                }
                At[kc + 0][row_a] = v0.x; At[kc + 1][row_a] = v0.y;
                At[kc + 2][row_a] = v0.z; At[kc + 3][row_a] = v0.w;
                At[kc + 4][row_a] = v1.x; At[kc + 5][row_a] = v1.y;
                At[kc + 6][row_a] = v1.z; At[kc + 7][row_a] = v1.w;
            }
            {
                const float* wrow = W + (size_t)(k0 + kb) * HD + cb;
                *(float4*)&Bt[kb][cb + 0]  = *(const float4*)(wrow + 0);
                *(float4*)&Bt[kb][cb + 4]  = *(const float4*)(wrow + 4);
                *(float4*)&Bt[kb][cb + 8]  = *(const float4*)(wrow + 8);
                *(float4*)&Bt[kb][cb + 12] = *(const float4*)(wrow + 12);
            }
            __syncthreads();

            #pragma unroll
            for (int kk = 0; kk < 32; ++kk) {
                float4 bv = *(const float4*)&Bt[kk][cg * 4];
                float4 a0 = *(const float4*)&At[kk][rg * 8];
                float4 a1 = *(const float4*)&At[kk][rg * 8 + 4];
                float av[8] = {a0.x, a0.y, a0.z, a0.w, a1.x, a1.y, a1.z, a1.w};
                float bw[4] = {bv.x, bv.y, bv.z, bv.w};
                #pragma unroll
                for (int i = 0; i < 8; ++i)
                    #pragma unroll
                    for (int j = 0; j < 4; ++j)
                        acc[i][j] += av[i] * bw[j];
            }
        }
    }

    #pragma unroll
    for (int i = 0; i < 8; ++i) {
        int r = row0 + rg * 8 + i;
        if (r < N) {
            float4 o;
            o.x = fmaxf(acc[i][0], 0.f);
            o.y = fmaxf(acc[i][1], 0.f);
            o.z = fmaxf(acc[i][2], 0.f);
            o.w = fmaxf(acc[i][3], 0.f);
            *(float4*)(h + (size_t)r * HD + cg * 4) = o;
        }
    }
}

// gate[i] = dot(h[i], gate_w) + gate_b  (wave per row)
__global__ void gate_kernel(const float* __restrict__ h, const float* __restrict__ gw,
                            const float* __restrict__ gb, float* __restrict__ gate, int N) {
    int wid  = (blockIdx.x * blockDim.x + threadIdx.x) >> 6;
    int lane = threadIdx.x & 63;
    int nw   = (gridDim.x * blockDim.x) >> 6;
    float2 w = ((const float2*)gw)[lane];
    for (int row = wid; row < N; row += nw) {
        float2 v = ((const float2*)(h + (size_t)row * HD))[lane];
        float s = v.x * w.x + v.y * w.y;
        for (int off = 32; off; off >>= 1) s += __shfl_xor(s, off);
        if (lane == 0) gate[row] = s + gb[0];
    }
}

__device__ __forceinline__ int lower_bound_i(const int* a, int n, int key) {
    int lo = 0, hi = n;
    while (lo < hi) { int mid = (lo + hi) >> 1; if (a[mid] < key) lo = mid + 1; else hi = mid; }
    return lo;
}

// per-graph softmax-weighted pooling; block per graph, batch sorted.
__global__ __launch_bounds__(128) void pool_kernel(
    const float* __restrict__ h, const float* __restrict__ gate,
    const int* __restrict__ batch, float* __restrict__ pooled, int N)
{
    int g = blockIdx.x;
    int t = threadIdx.x;
    int start = lower_bound_i(batch, N, g);
    int end   = lower_bound_i(batch, N, g + 1);
    __shared__ float sred[128];

    float m = -3.4e38f;
    for (int i = start + t; i < end; i += 128) m = fmaxf(m, gate[i]);
    sred[t] = m; __syncthreads();
    for (int s = 64; s; s >>= 1) { if (t < s) sred[t] = fmaxf(sred[t], sred[t + s]); __syncthreads(); }
    float gmax = sred[0]; __syncthreads();

    float ss = 0.f;
    for (int i = start + t; i < end; i += 128) ss += __expf(gate[i] - gmax);
    sred[t] = ss; __syncthreads();
    for (int s = 64; s; s >>= 1) { if (t < s) sred[t] += sred[t + s]; __syncthreads(); }
    float denom = sred[0]; __syncthreads();

    float acc = 0.f;
    for (int base = start; base < end; base += 128) {
        int cnt = min(128, end - base);
        if (t < cnt) sred[t] = __expf(gate[base + t] - gmax);
        __syncthreads();
        for (int i = 0; i < cnt; ++i)
            acc += h[(size_t)(base + i) * HD + t] * sred[i];
        __syncthreads();
    }
    pooled[(size_t)g * HD + t] = (end > start) ? acc / denom : 0.f;
}

// MLP head: out = sigmoid(relu(pooled @ lin1 + b1) @ lin2 + b2); block per graph.
__global__ __launch_bounds__(128) void head_kernel(
    const float* __restrict__ pooled,
    const float* __restrict__ w1, const float* __restrict__ b1,
    const float* __restrict__ w2, const float* __restrict__ b2,
    float* __restrict__ out)
{
    int g = blockIdx.x, t = threadIdx.x;
    __shared__ float sp[128];
    __shared__ float sh[128];
    sp[t] = pooled[(size_t)g * HD + t];
    __syncthreads();
    float acc = b1[t];
    for (int k = 0; k < HD; ++k) acc += sp[k] * w1[k * HD + t];
    sh[t] = fmaxf(acc, 0.f);
    __syncthreads();
    if (t < 2) {
        float a = b2[t];
        for (int k = 0; k < HD; ++k) a += sh[k] * w2[k * 2 + t];
        out[g * 2 + t] = 1.f / (1.f + __expf(-a));
    }
}

// ---------------------------------------------------------------------------
extern "C" void kernel_launch(void* const* d_in, const int* in_sizes, int n_in,
                              void* d_out, int out_size, void* d_ws, size_t ws_size,
                              hipStream_t stream) {
    const float* x      = (const float*)d_in[0];
    const void*  eidx   = d_in[1];
    const void*  batchp = d_in[2];
    const float* w1_l   = (const float*)d_in[3];
    const float* b1     = (const float*)d_in[4];
    const float* w1_r   = (const float*)d_in[5];
    const float* ws_l   = (const float*)d_in[6];
    const float* bs     = (const float*)d_in[7];
    const float* ws_r   = (const float*)d_in[8];
    const float* gate_w = (const float*)d_in[9];
    const float* gate_b = (const float*)d_in[10];
    const float* lin1_w = (const float*)d_in[11];
    const float* lin1_b = (const float*)d_in[12];
    const float* lin2_w = (const float*)d_in[13];
    const float* lin2_b = (const float*)d_in[14];

    const int N = in_sizes[2];        // 100000
    const int E = in_sizes[1] / 2;    // 1600000
    const int G = out_size / 2;       // 512

    // workspace layout
    char* w = (char*)d_ws;
    int*   flag       = (int*)w;                      // 256 B block
    int*   blk_sum    = flag + 16;                    // 128 ints (within 256B+512B pad)
    int*   idx32      = (int*)(w + 1024);             // 2E
    int*   sorted_src = idx32 + 2 * (size_t)E;        // E
    int*   batch32    = sorted_src + E;               // N
    int*   cnt        = batch32 + N;                  // N
    int*   cursor     = cnt + N;                      // N
    float* inv_deg    = (float*)(cursor + N);         // N
    float* gate       = inv_deg + N;                  // N
    float* pooled     = gate + N;                     // G*HD
    float* B1         = pooled + (size_t)G * HD;      // N*HD
    float* B2         = B1 + (size_t)N * HD;          // N*HD
    int*   row_ptr    = (int*)(B2 + (size_t)N * HD);  // N+1

    const int* src = idx32;
    const int* dst = idx32 + E;

    // index conversion
    detect_i64_kernel<<<1, 64, 0, stream>>>((const unsigned*)eidx, flag);
    convert_idx_kernel<<<2048, 256, 0, stream>>>(eidx, idx32, 2 * E, flag);
    convert_idx_kernel<<<512, 256, 0, stream>>>(batchp, batch32, N, flag);

    // CSR build (once; shared by all 3 layers)
    const int nb = (N + 1023) / 1024;   // 98 blocks
    hipMemsetAsync(cnt, 0, (size_t)N * 4, stream);
    count_kernel<<<2048, 256, 0, stream>>>(dst, cnt, E);
    scan1_kernel<<<nb, 1024, 0, stream>>>(cnt, row_ptr, inv_deg, blk_sum, N);
    scan2_kernel<<<1, 128, 0, stream>>>(blk_sum, nb);
    scan3_kernel<<<nb, 1024, 0, stream>>>(row_ptr, blk_sum, N, E);
    copy_int_kernel<<<512, 256, 0, stream>>>(row_ptr, cursor, N);
    fill_kernel<<<2048, 256, 0, stream>>>(src, dst, cursor, sorted_src, E);

    const int gather_grid = (N * 64 + 255) / 256;   // one wave per node
    const int gemm_grid   = (N + 63) / 64;

    // layer 1: in = x -> mean in B1 -> h1 in-place in B1
    gather_kernel<<<gather_grid, 256, 0, stream>>>(x, row_ptr, sorted_src, inv_deg, B1, N);
    sage_layer_kernel<<<gemm_grid, 256, 0, stream>>>(x, B1, w1_l, b1, w1_r, N);

    // layer 2: in = B1 -> mean in B2 -> h2 in-place in B2
    gather_kernel<<<gather_grid, 256, 0, stream>>>(B1, row_ptr, sorted_src, inv_deg, B2, N);
    sage_layer_kernel<<<gemm_grid, 256, 0, stream>>>(B1, B2, ws_l, bs, ws_r, N);

    // layer 3: in = B2 -> mean in B1 -> h3 in-place in B1
    gather_kernel<<<gather_grid, 256, 0, stream>>>(B2, row_ptr, sorted_src, inv_deg, B1, N);
    sage_layer_kernel<<<gemm_grid, 256, 0, stream>>>(B2, B1,
                                                     ws_l + HD * HD, bs + HD, ws_r + HD * HD, N);

    // gate -> pool -> head
    gate_kernel<<<1024, 256, 0, stream>>>(B1, gate_w, gate_b, gate, N);
    pool_kernel<<<G, 128, 0, stream>>>(B1, gate, batch32, pooled, N);
    head_kernel<<<G, 128, 0, stream>>>(pooled, lin1_w, lin1_b, lin2_w, lin2_b, (float*)d_out);
}